// Round 4
// baseline (179.280 us; speedup 1.0000x reference)
//
#include <hip/hip_runtime.h>
#include <hip/hip_bf16.h>

// NonLocalBlock fp32 -> split-bf16 MFMA, MI355X. Sizes fixed by the reference.
#define BATCH 2
#define CIN   64
#define COUT  32
#define HW    6400           // 80*80
#define PB    (COUT*HW)      // 204800 elems per batch for T/P/G (M-view 6400x32)
#define XB    (CIN*HW)       // 409600 elems per batch for x / z

typedef __attribute__((ext_vector_type(8))) short  bf16x8;  // MFMA A/B frag (4 VGPR)
typedef __attribute__((ext_vector_type(4))) float  f32x4;   // MFMA C/D frag

typedef unsigned short ushort;
typedef unsigned int   uint;

__device__ inline uint pk2(float a, float b) {
  // pack 2 floats -> 2 bf16 (RTNE), low short = a
  __hip_bfloat162 h = __float22bfloat162_rn(make_float2(a, b));
  union { __hip_bfloat162 h2; uint u; } cv; cv.h2 = h;
  return cv.u;
}
__device__ inline float up_lo(uint u) { return __uint_as_float(u << 16); }
__device__ inline float up_hi(uint u) { return __uint_as_float(u & 0xFFFF0000u); }

#define MFMA16(a, bop, c) __builtin_amdgcn_mfma_f32_16x16x32_bf16((a), (bop), (c), 0, 0, 0)

// ---------------------------------------------------------------------------
// Kernel 1: three 1x1 convs -> bf16 hi/lo split flat buffers.
// ---------------------------------------------------------------------------
__global__ __launch_bounds__(256) void conv3_kernel(
    const float* __restrict__ x,
    const float* __restrict__ w0, const float* __restrict__ bb0,   // theta
    const float* __restrict__ w1, const float* __restrict__ bb1,   // phi
    const float* __restrict__ w2, const float* __restrict__ bb2,   // g
    ushort* __restrict__ T_hi, ushort* __restrict__ T_lo,
    ushort* __restrict__ P_hi, ushort* __restrict__ P_lo,
    ushort* __restrict__ G_hi, ushort* __restrict__ G_lo) {
  const int which = blockIdx.y;
  const float* w  = (which == 0) ? w0 : (which == 1) ? w1 : w2;
  const float* bv = (which == 0) ? bb0 : (which == 1) ? bb1 : bb2;
  ushort* ohi = (which == 0) ? T_hi : (which == 1) ? P_hi : G_hi;
  ushort* olo = (which == 0) ? T_lo : (which == 1) ? P_lo : G_lo;
  const int b = blockIdx.z;
  const int s = blockIdx.x * 256 + threadIdx.x;   // 25*256 == 6400

  __shared__ float wsm[COUT * CIN];               // 8 KiB
  for (int i = threadIdx.x; i < COUT * CIN; i += 256) wsm[i] = w[i];
  __syncthreads();

  float xr[CIN];
#pragma unroll
  for (int c = 0; c < CIN; ++c) xr[c] = x[b * XB + c * HW + s];   // coalesced

  for (int o = 0; o < COUT; ++o) {
    const float4* wr = (const float4*)&wsm[o * CIN];
    float acc = 0.f;
#pragma unroll
    for (int q = 0; q < CIN / 4; ++q) {
      float4 wv = wr[q];
      acc += wv.x * xr[4*q] + wv.y * xr[4*q+1] + wv.z * xr[4*q+2] + wv.w * xr[4*q+3];
    }
    acc += bv[o];
    const int f = b * PB + o * HW + s;
    uint hb = pk2(acc, 0.f) & 0xFFFFu;            // bf16(acc) bits
    float hf = __uint_as_float(hb << 16);
    uint lb = pk2(acc - hf, 0.f) & 0xFFFFu;
    ohi[f] = (ushort)hb;
    olo[f] = (ushort)lb;
  }
}

// ---------------------------------------------------------------------------
// Kernel 2: permuted transpose of G: Gt[b][c][n'] = G_M[(n'&~31)+sigma(n'&31)][c]
// sigma(p) = 4*(p>>3) + (p&3) + 16*((p>>2)&1)  (PV slot->key map, bijective /32)
// ---------------------------------------------------------------------------
__global__ __launch_bounds__(256) void transpose_g_kernel(
    const ushort* __restrict__ G_hi, const ushort* __restrict__ G_lo,
    ushort* __restrict__ Gt_hi, ushort* __restrict__ Gt_lo) {
  const int b = blockIdx.y;
  const int o = blockIdx.x * 256 + threadIdx.x;   // 0..25600
  const int c   = o / 800;
  const int n0  = (o % 800) * 8;

  ushort vh[8], vl[8];
#pragma unroll
  for (int j = 0; j < 8; ++j) {
    int np = n0 + j;
    int p  = np & 31;
    int ns = (np & ~31) + 4*(p>>3) + (p&3) + 16*((p>>2)&1);
    int src = b * PB + ns * 32 + c;
    vh[j] = G_hi[src];
    vl[j] = G_lo[src];
  }
  const int dst = b * PB + c * HW + n0;
#pragma unroll
  for (int j = 0; j < 8; ++j) { Gt_hi[dst + j] = vh[j]; Gt_lo[dst + j] = vl[j]; }
}

// ---------------------------------------------------------------------------
// Kernel 3: fused attention, split-bf16 MFMA.
// grid (200 q-tiles, 2 key-halves, B) x 512 threads (8 waves).
// Block owns 32 queries and HALF the keys (split-K exact: raw-exp partials
// combine linearly; combine happens in conv_out).
// wave w: wq = w>>2 (q-subtile of 16), wk = w&3; key-groups kt = ks*100+wk+4i,
// 25 iterations. Register double-buffer: G loads at top (hidden under QK+exp),
// next P fragments prefetched right after QK consumes the current ones.
// ---------------------------------------------------------------------------
__global__ __launch_bounds__(512, 6) void attn_kernel(
    const ushort* __restrict__ T_hi, const ushort* __restrict__ T_lo,
    const ushort* __restrict__ P_hi, const ushort* __restrict__ P_lo,
    const ushort* __restrict__ Gt_hi, const ushort* __restrict__ Gt_lo,
    float* __restrict__ Yp,   // [2][B][HW][32] partial sums
    float* __restrict__ Dp) { // [2][B][HW]     partial denominators
  const int b     = blockIdx.z;
  const int ks    = blockIdx.y;          // key half 0/1
  const int q_blk = blockIdx.x;          // 0..199
  const int tid   = threadIdx.x;
  const int w     = tid >> 6;            // wave 0..7
  const int lane  = tid & 63;
  const int wq    = w >> 2;              // 0..1
  const int wk    = w & 3;               // 0..3
  const int l15   = lane & 15;
  const int g     = lane >> 4;           // 0..3

  __shared__ float ylds[8][16][33];      // 16.9 KiB (pad kills bank conflicts)
  __shared__ float dlds[8][16];

  // T fragment (B-operand of QK): row q, chans g*8..+8, loaded once
  const int qrow = q_blk * 32 + wq * 16 + l15;
  const bf16x8 t_hi = *(const bf16x8*)&T_hi[b * PB + qrow * 32 + g * 8];
  const bf16x8 t_lo = *(const bf16x8*)&T_lo[b * PB + qrow * 32 + g * 8];

  f32x4 acc0 = {0.f, 0.f, 0.f, 0.f};     // chans 0..15  (query rows 4g+r)
  f32x4 acc1 = {0.f, 0.f, 0.f, 0.f};     // chans 16..31
  float denom = 0.f;

  int kt = ks * 100 + wk;

  // preload first group's P fragments (A-operand): rows kt*32+l15 / +16
  int pa = b * PB + (kt * 32 + l15) * 32 + g * 8;
  bf16x8 pa_hi = *(const bf16x8*)&P_hi[pa];
  bf16x8 pa_lo = *(const bf16x8*)&P_lo[pa];
  bf16x8 pb_hi = *(const bf16x8*)&P_hi[pa + 512];   // +16 rows
  bf16x8 pb_lo = *(const bf16x8*)&P_lo[pa + 512];

  for (int i = 0; i < 25; ++i) {
    const int m0 = kt * 32;

    // Gt fragments for current group (latency hides under QK + exp/pack)
    const int ga = b * PB + l15 * HW + m0 + g * 8;
    const bf16x8 g0_hi = *(const bf16x8*)&Gt_hi[ga];
    const bf16x8 g0_lo = *(const bf16x8*)&Gt_lo[ga];
    const bf16x8 g1_hi = *(const bf16x8*)&Gt_hi[ga + 16 * HW];
    const bf16x8 g1_lo = *(const bf16x8*)&Gt_lo[ga + 16 * HW];

    // QK^T (swapped): S^T = P . T^T, split products hh + hl + lh
    f32x4 sa = {0.f, 0.f, 0.f, 0.f};
    f32x4 sb = {0.f, 0.f, 0.f, 0.f};
    sa = MFMA16(pa_hi, t_hi, sa);
    sa = MFMA16(pa_hi, t_lo, sa);
    sa = MFMA16(pa_lo, t_hi, sa);
    sb = MFMA16(pb_hi, t_hi, sb);
    sb = MFMA16(pb_hi, t_lo, sb);
    sb = MFMA16(pb_lo, t_hi, sb);

    // prefetch NEXT group's P fragments (current ones are consumed above)
    const int ktn = (i < 24) ? kt + 4 : kt;
    const int pan = b * PB + (ktn * 32 + l15) * 32 + g * 8;
    pa_hi = *(const bf16x8*)&P_hi[pan];
    pa_lo = *(const bf16x8*)&P_lo[pan];
    pb_hi = *(const bf16x8*)&P_hi[pan + 512];
    pb_lo = *(const bf16x8*)&P_lo[pan + 512];

    // exp (scores ~O(0.15); reference uses raw exp — no max subtraction)
    const float ea0 = __expf(sa[0]), ea1 = __expf(sa[1]);
    const float ea2 = __expf(sa[2]), ea3 = __expf(sa[3]);
    const float eb0 = __expf(sb[0]), eb1 = __expf(sb[1]);
    const float eb2 = __expf(sb[2]), eb3 = __expf(sb[3]);
    denom += ((ea0 + ea1) + (ea2 + ea3)) + ((eb0 + eb1) + (eb2 + eb3));

    // split exp'd P into hi/lo bf16x8 A-frags; slot order [ea r0..3, eb r0..3]
    union { uint u[4]; bf16x8 v; } ph, pl;
    ph.u[0] = pk2(ea0, ea1); ph.u[1] = pk2(ea2, ea3);
    ph.u[2] = pk2(eb0, eb1); ph.u[3] = pk2(eb2, eb3);
    pl.u[0] = pk2(ea0 - up_lo(ph.u[0]), ea1 - up_hi(ph.u[0]));
    pl.u[1] = pk2(ea2 - up_lo(ph.u[1]), ea3 - up_hi(ph.u[1]));
    pl.u[2] = pk2(eb0 - up_lo(ph.u[2]), eb1 - up_hi(ph.u[2]));
    pl.u[3] = pk2(eb2 - up_lo(ph.u[3]), eb3 - up_hi(ph.u[3]));

    // PV: Y += P_exp . G  (Gt stored key-permuted so B slot k == A slot k)
    acc0 = MFMA16(ph.v, g0_hi, acc0);
    acc0 = MFMA16(ph.v, g0_lo, acc0);
    acc0 = MFMA16(pl.v, g0_hi, acc0);
    acc1 = MFMA16(ph.v, g1_hi, acc1);
    acc1 = MFMA16(ph.v, g1_lo, acc1);
    acc1 = MFMA16(pl.v, g1_hi, acc1);

    kt = ktn;
  }

  // per-wave denominator for query l15: sum the 4 key-slots (g) in-wave
  denom += __shfl_xor(denom, 16);
  denom += __shfl_xor(denom, 32);

  // stash per-wave partials
#pragma unroll
  for (int r = 0; r < 4; ++r) {
    ylds[w][4 * g + r][l15]      = acc0[r];
    ylds[w][4 * g + r][16 + l15] = acc1[r];
  }
  if (g == 0) dlds[w][l15] = denom;
  __syncthreads();

  // combine across wk waves; write RAW partials (normalize happens in conv_out)
  const int c  = tid & 31;
  const int qq = (tid >> 5) & 15;
#pragma unroll
  for (int wqi = 0; wqi < 2; ++wqi) {
    float y = 0.f, d = 0.f;
#pragma unroll
    for (int k2 = 0; k2 < 4; ++k2) {
      y += ylds[wqi * 4 + k2][qq][c];
      d += dlds[wqi * 4 + k2][qq];
    }
    const int row = q_blk * 32 + wqi * 16 + qq;
    Yp[((size_t)(ks * BATCH + b)) * PB + row * 32 + c] = y;
    if (c == 0) Dp[((size_t)(ks * BATCH + b)) * HW + row] = d;
  }
}

// ---------------------------------------------------------------------------
// Kernel 4: final 1x1 conv, fused with key-half combine + softmax normalize.
// yview[b][o][s] = (Yp0[f]+Yp1[f]) / (Dp0[n]+Dp1[n]),  f = o*HW+s, n = f>>5.
// (exactly 2 float contributions -> order-independent -> deterministic)
// grid (25, B) x 256.
// ---------------------------------------------------------------------------
__global__ __launch_bounds__(256) void conv_out_kernel(
    const float* __restrict__ Yp, const float* __restrict__ Dp,
    const float* __restrict__ wy, const float* __restrict__ by,
    float* __restrict__ z) {
  const int b = blockIdx.y;
  const int s = blockIdx.x * 256 + threadIdx.x;

  __shared__ float wsm[CIN * COUT];   // 8 KiB, w_y is [CIN][COUT] row-major
  for (int i = threadIdx.x; i < CIN * COUT; i += 256) wsm[i] = wy[i];
  __syncthreads();

  float yr[COUT];
#pragma unroll
  for (int o = 0; o < COUT; ++o) {
    const int f = o * HW + s;
    const int n = f >> 5;
    const float y0 = Yp[(size_t)b * PB + f];
    const float y1 = Yp[((size_t)BATCH + b) * PB + f];
    const float d  = Dp[(size_t)b * HW + n] + Dp[((size_t)BATCH + b) * HW + n];
    yr[o] = (y0 + y1) / d;
  }

  for (int i = 0; i < CIN; ++i) {
    const float4* wr = (const float4*)&wsm[i * COUT];
    float acc = 0.f;
#pragma unroll
    for (int q = 0; q < COUT / 4; ++q) {
      float4 wv = wr[q];
      acc += wv.x * yr[4*q] + wv.y * yr[4*q+1] + wv.z * yr[4*q+2] + wv.w * yr[4*q+3];
    }
    z[(size_t)b * XB + i * HW + s] = acc + by[i];
  }
}

// ---------------------------------------------------------------------------
extern "C" void kernel_launch(void* const* d_in, const int* in_sizes, int n_in,
                              void* d_out, int out_size, void* d_ws, size_t ws_size,
                              hipStream_t stream) {
  const float* x       = (const float*)d_in[0];
  const float* w_g     = (const float*)d_in[1];
  const float* b_g     = (const float*)d_in[2];
  const float* w_phi   = (const float*)d_in[3];
  const float* b_phi   = (const float*)d_in[4];
  const float* w_theta = (const float*)d_in[5];
  const float* b_theta = (const float*)d_in[6];
  const float* w_y     = (const float*)d_in[7];
  const float* b_y     = (const float*)d_in[8];
  float* z = (float*)d_out;

  char* base = (char*)d_ws;
  const size_t BF = (size_t)BATCH * PB * sizeof(ushort);  // 819200 B
  ushort* T_hi  = (ushort*)(base);
  ushort* T_lo  = (ushort*)(base + 1 * BF);
  ushort* P_hi  = (ushort*)(base + 2 * BF);
  ushort* P_lo  = (ushort*)(base + 3 * BF);
  ushort* G_hi  = (ushort*)(base + 4 * BF);
  ushort* G_lo  = (ushort*)(base + 5 * BF);
  ushort* Gt_hi = (ushort*)(base + 6 * BF);
  ushort* Gt_lo = (ushort*)(base + 7 * BF);
  float*  Yp    = (float*)(base + 8 * BF);                        // 2*B*PB f32
  float*  Dp    = (float*)(base + 8 * BF + (size_t)2 * BATCH * PB * sizeof(float));

  conv3_kernel<<<dim3(25, 3, BATCH), 256, 0, stream>>>(
      x, w_theta, b_theta, w_phi, b_phi, w_g, b_g,
      T_hi, T_lo, P_hi, P_lo, G_hi, G_lo);
  transpose_g_kernel<<<dim3(100, BATCH), 256, 0, stream>>>(
      G_hi, G_lo, Gt_hi, Gt_lo);
  attn_kernel<<<dim3(200, 2, BATCH), 512, 0, stream>>>(
      T_hi, T_lo, P_hi, P_lo, Gt_hi, Gt_lo, Yp, Dp);
  conv_out_kernel<<<dim3(25, BATCH), 256, 0, stream>>>(Yp, Dp, w_y, b_y, z);
}

// Round 6
// 91.442 us; speedup vs baseline: 1.9606x; 1.9606x over previous
//
#include <hip/hip_runtime.h>
#include <hip/hip_bf16.h>

// NonLocalBlock fp32 -> split-bf16 MFMA, MI355X. Sizes fixed by the reference.
#define BATCH 2
#define CIN   64
#define COUT  32
#define HW    6400           // 80*80
#define PB    (COUT*HW)      // 204800 elems per batch for T/P/G (M-view 6400x32)
#define XB    (CIN*HW)       // 409600 elems per batch for x / z

typedef __attribute__((ext_vector_type(8))) short  bf16x8;  // MFMA A/B frag (4 VGPR)
typedef __attribute__((ext_vector_type(4))) float  f32x4;   // MFMA C/D frag

typedef unsigned short ushort;
typedef unsigned int   uint;

__device__ inline uint pk2(float a, float b) {
  // pack 2 floats -> 2 bf16 (RTNE), low short = a
  __hip_bfloat162 h = __float22bfloat162_rn(make_float2(a, b));
  union { __hip_bfloat162 h2; uint u; } cv; cv.h2 = h;
  return cv.u;
}
__device__ inline float up_lo(uint u) { return __uint_as_float(u << 16); }
__device__ inline float up_hi(uint u) { return __uint_as_float(u & 0xFFFF0000u); }

#define MFMA16(a, bop, c) __builtin_amdgcn_mfma_f32_16x16x32_bf16((a), (bop), (c), 0, 0, 0)

// async global(16B per lane) -> LDS(base + lane*16); dest must be wave-uniform
__device__ inline void gload16(const void* g, void* l) {
  __builtin_amdgcn_global_load_lds(
      (const __attribute__((address_space(1))) void*)g,
      (__attribute__((address_space(3))) void*)l, 16, 0, 0);
}

// ---------------------------------------------------------------------------
// Kernel 1: three 1x1 convs -> bf16 hi/lo split flat buffers (identity [o][s]
// layout for all three; the flat buffer IS the reference raw-reshape view).
// grid (25, 3, B), block 256.  [round-4 verified version]
// ---------------------------------------------------------------------------
__global__ __launch_bounds__(256) void conv3_kernel(
    const float* __restrict__ x,
    const float* __restrict__ w0, const float* __restrict__ bb0,   // theta
    const float* __restrict__ w1, const float* __restrict__ bb1,   // phi
    const float* __restrict__ w2, const float* __restrict__ bb2,   // g
    ushort* __restrict__ T_hi, ushort* __restrict__ T_lo,
    ushort* __restrict__ P_hi, ushort* __restrict__ P_lo,
    ushort* __restrict__ G_hi, ushort* __restrict__ G_lo) {
  const int which = blockIdx.y;
  const float* w  = (which == 0) ? w0 : (which == 1) ? w1 : w2;
  const float* bv = (which == 0) ? bb0 : (which == 1) ? bb1 : bb2;
  ushort* ohi = (which == 0) ? T_hi : (which == 1) ? P_hi : G_hi;
  ushort* olo = (which == 0) ? T_lo : (which == 1) ? P_lo : G_lo;
  const int b = blockIdx.z;
  const int s = blockIdx.x * 256 + threadIdx.x;   // 25*256 == 6400

  __shared__ float wsm[COUT * CIN];               // 8 KiB
  for (int i = threadIdx.x; i < COUT * CIN; i += 256) wsm[i] = w[i];
  __syncthreads();

  float xr[CIN];
#pragma unroll
  for (int c = 0; c < CIN; ++c) xr[c] = x[b * XB + c * HW + s];   // coalesced

  for (int o = 0; o < COUT; ++o) {
    const float4* wr = (const float4*)&wsm[o * CIN];
    float acc = 0.f;
#pragma unroll
    for (int q = 0; q < CIN / 4; ++q) {
      float4 wv = wr[q];
      acc += wv.x * xr[4*q] + wv.y * xr[4*q+1] + wv.z * xr[4*q+2] + wv.w * xr[4*q+3];
    }
    acc += bv[o];
    const int f = b * PB + o * HW + s;
    uint hb = pk2(acc, 0.f) & 0xFFFFu;            // bf16(acc) bits
    float hf = __uint_as_float(hb << 16);
    uint lb = pk2(acc - hf, 0.f) & 0xFFFFu;
    ohi[f] = (ushort)hb;
    olo[f] = (ushort)lb;
  }
}

// ---------------------------------------------------------------------------
// Kernel 2: permuted transpose of G: Gt[b][c][n'] = G_M[(n'&~31)+sigma(n'&31)][c]
// sigma(p) = 4*(p>>3) + (p&3) + 16*((p>>2)&1)  (PV slot->key map, bijective /32)
// [round-4 verified version]
// ---------------------------------------------------------------------------
__global__ __launch_bounds__(256) void transpose_g_kernel(
    const ushort* __restrict__ G_hi, const ushort* __restrict__ G_lo,
    ushort* __restrict__ Gt_hi, ushort* __restrict__ Gt_lo) {
  const int b = blockIdx.y;
  const int o = blockIdx.x * 256 + threadIdx.x;   // 0..25600
  const int c   = o / 800;
  const int n0  = (o % 800) * 8;

  ushort vh[8], vl[8];
#pragma unroll
  for (int j = 0; j < 8; ++j) {
    int np = n0 + j;
    int p  = np & 31;
    int ns = (np & ~31) + 4*(p>>3) + (p&3) + 16*((p>>2)&1);
    int src = b * PB + ns * 32 + c;
    vh[j] = G_hi[src];
    vl[j] = G_lo[src];
  }
  const int dst = b * PB + c * HW + n0;
#pragma unroll
  for (int j = 0; j < 8; ++j) { Gt_hi[dst + j] = vh[j]; Gt_lo[dst + j] = vl[j]; }
}

// ---------------------------------------------------------------------------
// Kernel 3: fused attention, split-bf16 MFMA, LDS-pipelined (2-phase dbuf).
// grid (100 q-tiles, 4 key-splits, B) x 512 threads (8 waves).
// Block owns 64 queries; wave w: wk=w&3 (key slice), h=w>>2 (q-pair + staging
// half). Each iter = 128 keys (4 slices x 32). Keys split 13/13/12/12 groups
// across blockIdx.y (exact: raw-exp partials combine linearly in conv_out).
//
// LDS per buffer (32KB): slice wk at wk*8KB:
//   [P_hi 2K][P_lo 2K][Gt_hi 2K][Gt_lo 2K] bytes, each [row/chan 32][32].
// Staging: wave w stages half h of slice wk = 4x global_load_lds(16B).
// Fragments (per round-3 verified layouts):
//   P A-frag:  rows l15/l15+16, chans g*8..   (QK swapped: S^T, col=query)
//   Gt B-frag: chans l15/16+l15, perm-keys g*8..
// ---------------------------------------------------------------------------
__global__ __launch_bounds__(512, 4) void attn_kernel(
    const ushort* __restrict__ T_hi, const ushort* __restrict__ T_lo,
    const ushort* __restrict__ P_hi, const ushort* __restrict__ P_lo,
    const ushort* __restrict__ Gt_hi, const ushort* __restrict__ Gt_lo,
    float* __restrict__ Yp,   // [4][B][HW][32] partial sums
    float* __restrict__ Dp) { // [4][B][HW]     partial denominators
  const int b     = blockIdx.z;
  const int ks    = blockIdx.y;          // key split 0..3
  const int q_blk = blockIdx.x;          // 0..99 (64 queries each)
  const int tid   = threadIdx.x;
  const int w     = tid >> 6;            // wave 0..7
  const int lane  = tid & 63;
  const int wk    = w & 3;               // key slice
  const int h     = w >> 2;              // staging half / q-pair selector
  const int l15   = lane & 15;
  const int g     = lane >> 4;           // 0..3

  __shared__ __align__(16) ushort smem[2][16384];   // 2 x 32 KB

  const int gstart = (ks < 2) ? ks * 13 : 26 + (ks - 2) * 12;
  const int niter  = (ks < 2) ? 13 : 12;

  // T fragments for this wave's two q-subtiles qs = h*2+s2
  bf16x8 t_hi[2], t_lo[2];
#pragma unroll
  for (int s2 = 0; s2 < 2; ++s2) {
    const int qrow = q_blk * 64 + (h * 2 + s2) * 16 + l15;
    t_hi[s2] = *(const bf16x8*)&T_hi[b * PB + qrow * 32 + g * 8];
    t_lo[s2] = *(const bf16x8*)&T_lo[b * PB + qrow * 32 + g * 8];
  }

  // staging global bases (ushort elem indices), advance per iter
  const int rb0 = (gstart * 128 + wk * 32 + h * 16) * 32;   // P rows base*32
  const ushort* pgh = P_hi + b * PB + rb0 + lane * 8;        // +4096/iter
  const ushort* pgl = P_lo + b * PB + rb0 + lane * 8;
  const int gc = h * 16 + (lane >> 2);                       // Gt chan row
  const int gk0 = gstart * 128 + wk * 32 + (lane & 3) * 8;   // +128/iter
  const ushort* ggh = Gt_hi + b * PB + gc * HW + gk0;
  const ushort* ggl = Gt_lo + b * PB + gc * HW + gk0;
  // wave-uniform LDS staging dest (ushort offset)
  const int ldst = wk * 4096 + h * 512;

  f32x4 acc0[2] = {{0.f,0.f,0.f,0.f},{0.f,0.f,0.f,0.f}};  // chans 0..15
  f32x4 acc1[2] = {{0.f,0.f,0.f,0.f},{0.f,0.f,0.f,0.f}};  // chans 16..31
  float denom[2] = {0.f, 0.f};

  // prologue: stage iter 0 into buf 0
  {
    ushort* ld = &smem[0][ldst];
    gload16(pgh, ld);           gload16(pgl, ld + 1024);
    gload16(ggh, ld + 2048);    gload16(ggl, ld + 3072);
  }
  __syncthreads();

  int cur = 0;
  for (int i = 0; i < niter; ++i) {
    // stage NEXT iter into the other buffer (latency hides under compute)
    if (i + 1 < niter) {
      ushort* ld = &smem[cur ^ 1][ldst];
      gload16(pgh + (i+1) * 4096, ld);
      gload16(pgl + (i+1) * 4096, ld + 1024);
      gload16(ggh + (i+1) * 128,  ld + 2048);
      gload16(ggl + (i+1) * 128,  ld + 3072);
    }

    const char* base = (const char*)&smem[cur][0] + wk * 8192;
    const int fo = l15 * 64 + g * 16;
    const bf16x8 pa_hi = *(const bf16x8*)(base + fo);
    const bf16x8 pb_hi = *(const bf16x8*)(base + 1024 + fo);
    const bf16x8 pa_lo = *(const bf16x8*)(base + 2048 + fo);
    const bf16x8 pb_lo = *(const bf16x8*)(base + 3072 + fo);
    const bf16x8 g0_hi = *(const bf16x8*)(base + 4096 + fo);
    const bf16x8 g1_hi = *(const bf16x8*)(base + 5120 + fo);
    const bf16x8 g0_lo = *(const bf16x8*)(base + 6144 + fo);
    const bf16x8 g1_lo = *(const bf16x8*)(base + 7168 + fo);

#pragma unroll
    for (int s2 = 0; s2 < 2; ++s2) {
      // QK^T (swapped): S^T = P . T^T, splits hh + hl + lh
      f32x4 sa = {0.f,0.f,0.f,0.f};
      f32x4 sb = {0.f,0.f,0.f,0.f};
      sa = MFMA16(pa_hi, t_hi[s2], sa);
      sa = MFMA16(pa_hi, t_lo[s2], sa);
      sa = MFMA16(pa_lo, t_hi[s2], sa);
      sb = MFMA16(pb_hi, t_hi[s2], sb);
      sb = MFMA16(pb_hi, t_lo[s2], sb);
      sb = MFMA16(pb_lo, t_hi[s2], sb);

      const float ea0 = __expf(sa[0]), ea1 = __expf(sa[1]);
      const float ea2 = __expf(sa[2]), ea3 = __expf(sa[3]);
      const float eb0 = __expf(sb[0]), eb1 = __expf(sb[1]);
      const float eb2 = __expf(sb[2]), eb3 = __expf(sb[3]);
      denom[s2] += ((ea0 + ea1) + (ea2 + ea3)) + ((eb0 + eb1) + (eb2 + eb3));

      union { uint u[4]; bf16x8 v; } ph, pl;
      ph.u[0] = pk2(ea0, ea1); ph.u[1] = pk2(ea2, ea3);
      ph.u[2] = pk2(eb0, eb1); ph.u[3] = pk2(eb2, eb3);
      pl.u[0] = pk2(ea0 - up_lo(ph.u[0]), ea1 - up_hi(ph.u[0]));
      pl.u[1] = pk2(ea2 - up_lo(ph.u[1]), ea3 - up_hi(ph.u[1]));
      pl.u[2] = pk2(eb0 - up_lo(ph.u[2]), eb1 - up_hi(ph.u[2]));
      pl.u[3] = pk2(eb2 - up_lo(ph.u[3]), eb3 - up_hi(ph.u[3]));

      acc0[s2] = MFMA16(ph.v, g0_hi, acc0[s2]);
      acc0[s2] = MFMA16(ph.v, g0_lo, acc0[s2]);
      acc0[s2] = MFMA16(pl.v, g0_hi, acc0[s2]);
      acc1[s2] = MFMA16(ph.v, g1_hi, acc1[s2]);
      acc1[s2] = MFMA16(ph.v, g1_lo, acc1[s2]);
      acc1[s2] = MFMA16(pl.v, g1_hi, acc1[s2]);
    }

    __syncthreads();   // staged data landed; all reads of cur done
    cur ^= 1;
  }

  // epilogue: reuse staging LDS for the combine (all waves past final barrier)
  float* yl = (float*)&smem[0][0];        // [8][16][33]
  float* dl = yl + 8 * 16 * 33;           // [8][16]
  const int c  = tid & 31;
  const int qq = (tid >> 5) & 15;

#pragma unroll
  for (int s2 = 0; s2 < 2; ++s2) {
    float dn = denom[s2];
    dn += __shfl_xor(dn, 16);
    dn += __shfl_xor(dn, 32);
#pragma unroll
    for (int r = 0; r < 4; ++r) {
      yl[(w * 16 + 4 * g + r) * 33 + l15]      = acc0[s2][r];
      yl[(w * 16 + 4 * g + r) * 33 + 16 + l15] = acc1[s2][r];
    }
    if (g == 0) dl[w * 16 + l15] = dn;
    __syncthreads();

#pragma unroll
    for (int ws = 0; ws < 2; ++ws) {       // combine the 4 wk waves of half ws
      float y = 0.f, d = 0.f;
#pragma unroll
      for (int k2 = 0; k2 < 4; ++k2) {
        y += yl[((ws * 4 + k2) * 16 + qq) * 33 + c];
        d += dl[(ws * 4 + k2) * 16 + qq];
      }
      const int row = q_blk * 64 + (ws * 2 + s2) * 16 + qq;
      Yp[((size_t)(ks * BATCH + b)) * PB + row * 32 + c] = y;
      if (c == 0) Dp[((size_t)(ks * BATCH + b)) * HW + row] = d;
    }
    __syncthreads();
  }
}

// ---------------------------------------------------------------------------
// Kernel 4: final 1x1 conv fused with 4-way partial combine + normalize.
// yview[b][o][s] = sum_ks Yp / sum_ks Dp.  grid (25, B) x 256.
// ---------------------------------------------------------------------------
__global__ __launch_bounds__(256) void conv_out_kernel(
    const float* __restrict__ Yp, const float* __restrict__ Dp,
    const float* __restrict__ wy, const float* __restrict__ by,
    float* __restrict__ z) {
  const int b = blockIdx.y;
  const int s = blockIdx.x * 256 + threadIdx.x;

  __shared__ float wsm[CIN * COUT];   // 8 KiB, w_y is [CIN][COUT] row-major
  for (int i = threadIdx.x; i < CIN * COUT; i += 256) wsm[i] = wy[i];
  __syncthreads();

  float yr[COUT];
#pragma unroll
  for (int o = 0; o < COUT; ++o) {
    const int f = o * HW + s;
    const int n = f >> 5;
    float y = 0.f, d = 0.f;
#pragma unroll
    for (int ksi = 0; ksi < 4; ++ksi) {
      y += Yp[((size_t)(ksi * BATCH + b)) * PB + f];
      d += Dp[((size_t)(ksi * BATCH + b)) * HW + n];
    }
    yr[o] = y / d;
  }

  for (int i = 0; i < CIN; ++i) {
    const float4* wr = (const float4*)&wsm[i * COUT];
    float acc = 0.f;
#pragma unroll
    for (int q = 0; q < COUT / 4; ++q) {
      float4 wv = wr[q];
      acc += wv.x * yr[4*q] + wv.y * yr[4*q+1] + wv.z * yr[4*q+2] + wv.w * yr[4*q+3];
    }
    z[(size_t)b * XB + i * HW + s] = acc + by[i];
  }
}

// ---------------------------------------------------------------------------
extern "C" void kernel_launch(void* const* d_in, const int* in_sizes, int n_in,
                              void* d_out, int out_size, void* d_ws, size_t ws_size,
                              hipStream_t stream) {
  const float* x       = (const float*)d_in[0];
  const float* w_g     = (const float*)d_in[1];
  const float* b_g     = (const float*)d_in[2];
  const float* w_phi   = (const float*)d_in[3];
  const float* b_phi   = (const float*)d_in[4];
  const float* w_theta = (const float*)d_in[5];
  const float* b_theta = (const float*)d_in[6];
  const float* w_y     = (const float*)d_in[7];
  const float* b_y     = (const float*)d_in[8];
  float* z = (float*)d_out;

  char* base = (char*)d_ws;
  const size_t BF = (size_t)BATCH * PB * sizeof(ushort);  // 819200 B
  ushort* T_hi  = (ushort*)(base);
  ushort* T_lo  = (ushort*)(base + 1 * BF);
  ushort* P_hi  = (ushort*)(base + 2 * BF);
  ushort* P_lo  = (ushort*)(base + 3 * BF);
  ushort* G_hi  = (ushort*)(base + 4 * BF);
  ushort* G_lo  = (ushort*)(base + 5 * BF);
  ushort* Gt_hi = (ushort*)(base + 6 * BF);
  ushort* Gt_lo = (ushort*)(base + 7 * BF);
  float*  Yp    = (float*)(base + 8 * BF);                        // 4*B*PB f32
  float*  Dp    = (float*)(base + 8 * BF + (size_t)4 * BATCH * PB * sizeof(float));

  conv3_kernel<<<dim3(25, 3, BATCH), 256, 0, stream>>>(
      x, w_theta, b_theta, w_phi, b_phi, w_g, b_g,
      T_hi, T_lo, P_hi, P_lo, G_hi, G_lo);
  transpose_g_kernel<<<dim3(100, BATCH), 256, 0, stream>>>(
      G_hi, G_lo, Gt_hi, Gt_lo);
  attn_kernel<<<dim3(100, 4, BATCH), 512, 0, stream>>>(
      T_hi, T_lo, P_hi, P_lo, Gt_hi, Gt_lo, Yp, Dp);
  conv_out_kernel<<<dim3(25, BATCH), 256, 0, stream>>>(Yp, Dp, w_y, b_y, z);
}

// Round 7
// 83.686 us; speedup vs baseline: 2.1423x; 1.0927x over previous
//
#include <hip/hip_runtime.h>
#include <hip/hip_bf16.h>

// NonLocalBlock fp32 -> split-bf16 MFMA, MI355X. Sizes fixed by the reference.
#define BATCH 2
#define CIN   64
#define COUT  32
#define HW    6400           // 80*80
#define PB    (COUT*HW)      // 204800 elems per batch for T/P/G (M-view 6400x32)
#define XB    (CIN*HW)       // 409600 elems per batch for x / z
#define KSPLIT 5             // key splits (exact: raw-exp partials add linearly)

typedef __attribute__((ext_vector_type(8))) short  bf16x8;  // MFMA A/B frag (4 VGPR)
typedef __attribute__((ext_vector_type(4))) float  f32x4;   // MFMA C/D frag

typedef unsigned short ushort;
typedef unsigned int   uint;

__device__ inline uint pk2(float a, float b) {
  // pack 2 floats -> 2 bf16 (RTNE), low short = a
  __hip_bfloat162 h = __float22bfloat162_rn(make_float2(a, b));
  union { __hip_bfloat162 h2; uint u; } cv; cv.h2 = h;
  return cv.u;
}
__device__ inline float up_lo(uint u) { return __uint_as_float(u << 16); }
__device__ inline float up_hi(uint u) { return __uint_as_float(u & 0xFFFF0000u); }

#define MFMA16(a, bop, c) __builtin_amdgcn_mfma_f32_16x16x32_bf16((a), (bop), (c), 0, 0, 0)

// async global(16B per lane) -> LDS(base + lane*16); dest must be wave-uniform
__device__ inline void gload16(const void* g, void* l) {
  __builtin_amdgcn_global_load_lds(
      (const __attribute__((address_space(1))) void*)g,
      (__attribute__((address_space(3))) void*)l, 16, 0, 0);
}

// ---------------------------------------------------------------------------
// Kernel 1: three 1x1 convs -> bf16 hi/lo split flat buffers (identity [o][s]
// layout; the flat buffer IS the reference raw-reshape view). [verified r4]
// grid (25, 3, B), block 256.
// ---------------------------------------------------------------------------
__global__ __launch_bounds__(256) void conv3_kernel(
    const float* __restrict__ x,
    const float* __restrict__ w0, const float* __restrict__ bb0,   // theta
    const float* __restrict__ w1, const float* __restrict__ bb1,   // phi
    const float* __restrict__ w2, const float* __restrict__ bb2,   // g
    ushort* __restrict__ T_hi, ushort* __restrict__ T_lo,
    ushort* __restrict__ P_hi, ushort* __restrict__ P_lo,
    ushort* __restrict__ G_hi, ushort* __restrict__ G_lo) {
  const int which = blockIdx.y;
  const float* w  = (which == 0) ? w0 : (which == 1) ? w1 : w2;
  const float* bv = (which == 0) ? bb0 : (which == 1) ? bb1 : bb2;
  ushort* ohi = (which == 0) ? T_hi : (which == 1) ? P_hi : G_hi;
  ushort* olo = (which == 0) ? T_lo : (which == 1) ? P_lo : G_lo;
  const int b = blockIdx.z;
  const int s = blockIdx.x * 256 + threadIdx.x;   // 25*256 == 6400

  __shared__ float wsm[COUT * CIN];               // 8 KiB
  for (int i = threadIdx.x; i < COUT * CIN; i += 256) wsm[i] = w[i];
  __syncthreads();

  float xr[CIN];
#pragma unroll
  for (int c = 0; c < CIN; ++c) xr[c] = x[b * XB + c * HW + s];   // coalesced

  for (int o = 0; o < COUT; ++o) {
    const float4* wr = (const float4*)&wsm[o * CIN];
    float acc = 0.f;
#pragma unroll
    for (int q = 0; q < CIN / 4; ++q) {
      float4 wv = wr[q];
      acc += wv.x * xr[4*q] + wv.y * xr[4*q+1] + wv.z * xr[4*q+2] + wv.w * xr[4*q+3];
    }
    acc += bv[o];
    const int f = b * PB + o * HW + s;
    uint hb = pk2(acc, 0.f) & 0xFFFFu;            // bf16(acc) bits
    float hf = __uint_as_float(hb << 16);
    uint lb = pk2(acc - hf, 0.f) & 0xFFFFu;
    ohi[f] = (ushort)hb;
    olo[f] = (ushort)lb;
  }
}

// ---------------------------------------------------------------------------
// Kernel 2: LDS-tiled permuted transpose of G:
//   Gt[b][c][n'] = G_M[(n'&~31) + sigma(n'&31)][c],
//   sigma(p) = 4*(p>>3) + (p&3) + 16*((p>>2)&1)   (bijective within /32)
// grid (200, B) x 256: block handles one 32-key group x 32 chans, hi+lo.
// Reads fully coalesced (2KB linear per buf); writes 8B per thread, 64B/row.
// ---------------------------------------------------------------------------
__global__ __launch_bounds__(256) void transpose_g_kernel(
    const ushort* __restrict__ G_hi, const ushort* __restrict__ G_lo,
    ushort* __restrict__ Gt_hi, ushort* __restrict__ Gt_lo) {
  const int b  = blockIdx.y;
  const int n0 = blockIdx.x * 32;       // key-group base (200*32 == 6400)
  const int t  = threadIdx.x;

  __shared__ ushort tile[2][1024];      // 4 KiB: [hi/lo][32 rows][32 chans]

  const int rbase = b * PB + n0 * 32;   // 2048B-aligned
  ((uint2*)tile[0])[t] = ((const uint2*)(G_hi + rbase))[t];   // 8B each
  ((uint2*)tile[1])[t] = ((const uint2*)(G_lo + rbase))[t];
  __syncthreads();

  const int c  = t >> 3;                // chan row 0..31
  const int p0 = (t & 7) * 4;           // key slot base
  ushort4 vh, vl;
  {
    int p, sp;
    p = p0 + 0; sp = 4*(p>>3) + (p&3) + 16*((p>>2)&1);
    vh.x = tile[0][sp*32 + c]; vl.x = tile[1][sp*32 + c];
    p = p0 + 1; sp = 4*(p>>3) + (p&3) + 16*((p>>2)&1);
    vh.y = tile[0][sp*32 + c]; vl.y = tile[1][sp*32 + c];
    p = p0 + 2; sp = 4*(p>>3) + (p&3) + 16*((p>>2)&1);
    vh.z = tile[0][sp*32 + c]; vl.z = tile[1][sp*32 + c];
    p = p0 + 3; sp = 4*(p>>3) + (p&3) + 16*((p>>2)&1);
    vh.w = tile[0][sp*32 + c]; vl.w = tile[1][sp*32 + c];
  }
  const int dst = b * PB + c * HW + n0 + p0;      // 8B-aligned
  *(ushort4*)(Gt_hi + dst) = vh;
  *(ushort4*)(Gt_lo + dst) = vl;
}

// ---------------------------------------------------------------------------
// Kernel 3: fused attention, split-bf16 MFMA, LDS-pipelined (2-phase dbuf).
// grid (100 q-tiles, KSPLIT, B) x 512 threads (8 waves).
// Block owns 64 queries; wave w: wk=w&3 (key slice), h=w>>2 (q-pair + staging
// half). Each iter = 128 keys (4 slices x 32); niter = 10 per split.
//
// LDS per buffer (32KB): slice wk at wk*8KB bytes:
//   [P_hi 2K][P_lo 2K][Gt_hi 2K][Gt_lo 2K]; each 2K region = 2 halves of 1KB.
// CONFLICT-FREE LAYOUT (r6): LDS chunk c (16B) of a wave's 1KB holds global
// (row = c&15, colchunk = c>>4). global_load_lds writes lane l -> chunk l
// linearly, so lane l's GLOBAL source is pre-permuted to (row l&15, chunk
// l>>4). Fragment reads then hit byte lane*16 -> linear, zero bank conflicts.
// Fragments (r3-verified math, unchanged):
//   P A-frag:  key rows l15 / l15+16, chans g*8..   (QK swapped: col=query)
//   Gt B-frag: chan rows l15 / 16+l15, perm-keys g*8..
// ---------------------------------------------------------------------------
__global__ __launch_bounds__(512, 4) void attn_kernel(
    const ushort* __restrict__ T_hi, const ushort* __restrict__ T_lo,
    const ushort* __restrict__ P_hi, const ushort* __restrict__ P_lo,
    const ushort* __restrict__ Gt_hi, const ushort* __restrict__ Gt_lo,
    float* __restrict__ Yp,   // [KSPLIT][B][HW][32] partial sums
    float* __restrict__ Dp) { // [KSPLIT][B][HW]     partial denominators
  const int b     = blockIdx.z;
  const int ks    = blockIdx.y;          // key split 0..KSPLIT-1
  const int q_blk = blockIdx.x;          // 0..99 (64 queries each)
  const int tid   = threadIdx.x;
  const int w     = tid >> 6;            // wave 0..7
  const int lane  = tid & 63;
  const int wk    = w & 3;               // key slice
  const int h     = w >> 2;              // staging half / q-pair selector
  const int l15   = lane & 15;
  const int g     = lane >> 4;           // 0..3

  __shared__ __align__(16) ushort smem[2][16384];   // 2 x 32 KB

  const int gstart = ks * 10;            // group = 128 keys; 50 groups total
  const int niter  = 10;

  // T fragments for this wave's two q-subtiles qs = h*2+s2
  bf16x8 t_hi[2], t_lo[2];
#pragma unroll
  for (int s2 = 0; s2 < 2; ++s2) {
    const int qrow = q_blk * 64 + (h * 2 + s2) * 16 + l15;
    t_hi[s2] = *(const bf16x8*)&T_hi[b * PB + qrow * 32 + g * 8];
    t_lo[s2] = *(const bf16x8*)&T_lo[b * PB + qrow * 32 + g * 8];
  }

  // staging global bases, PRE-PERMUTED per lane (see header comment):
  // P: lane l -> (key row rb0 + (l&15), chan chunk (l>>4)*8)
  const int rb0 = (gstart * 128 + wk * 32 + h * 16) * 32;
  const ushort* pgh = P_hi + b * PB + rb0 + (lane & 15) * 32 + (lane >> 4) * 8;
  const ushort* pgl = P_lo + b * PB + rb0 + (lane & 15) * 32 + (lane >> 4) * 8;
  // Gt: lane l -> (chan row h*16 + (l&15), perm-key chunk (l>>4)*8)
  const int gc  = h * 16 + (lane & 15);
  const int gk0 = gstart * 128 + wk * 32 + (lane >> 4) * 8;
  const ushort* ggh = Gt_hi + b * PB + gc * HW + gk0;
  const ushort* ggl = Gt_lo + b * PB + gc * HW + gk0;
  // wave-uniform LDS staging dest (ushort offset)
  const int ldst = wk * 4096 + h * 512;

  f32x4 acc0[2] = {{0.f,0.f,0.f,0.f},{0.f,0.f,0.f,0.f}};  // chans 0..15
  f32x4 acc1[2] = {{0.f,0.f,0.f,0.f},{0.f,0.f,0.f,0.f}};  // chans 16..31
  float denom[2] = {0.f, 0.f};

  // prologue: stage iter 0 into buf 0
  {
    ushort* ld = &smem[0][ldst];
    gload16(pgh, ld);           gload16(pgl, ld + 1024);
    gload16(ggh, ld + 2048);    gload16(ggl, ld + 3072);
  }
  __syncthreads();

  int cur = 0;
  for (int i = 0; i < niter; ++i) {
    // stage NEXT iter into the other buffer (latency hides under compute)
    if (i + 1 < niter) {
      ushort* ld = &smem[cur ^ 1][ldst];
      gload16(pgh + (i+1) * 4096, ld);
      gload16(pgl + (i+1) * 4096, ld + 1024);
      gload16(ggh + (i+1) * 128,  ld + 2048);
      gload16(ggl + (i+1) * 128,  ld + 3072);
    }

    // fragment reads: byte offset == lane*16 within each 1KB region -> linear
    const char* base = (const char*)&smem[cur][0] + wk * 8192;
    const int fo = g * 256 + l15 * 16;    // == lane*16
    const bf16x8 pa_hi = *(const bf16x8*)(base + fo);
    const bf16x8 pb_hi = *(const bf16x8*)(base + 1024 + fo);
    const bf16x8 pa_lo = *(const bf16x8*)(base + 2048 + fo);
    const bf16x8 pb_lo = *(const bf16x8*)(base + 3072 + fo);
    const bf16x8 g0_hi = *(const bf16x8*)(base + 4096 + fo);
    const bf16x8 g1_hi = *(const bf16x8*)(base + 5120 + fo);
    const bf16x8 g0_lo = *(const bf16x8*)(base + 6144 + fo);
    const bf16x8 g1_lo = *(const bf16x8*)(base + 7168 + fo);

#pragma unroll
    for (int s2 = 0; s2 < 2; ++s2) {
      // QK^T (swapped): S^T = P . T^T, splits hh + hl + lh
      f32x4 sa = {0.f,0.f,0.f,0.f};
      f32x4 sb = {0.f,0.f,0.f,0.f};
      __builtin_amdgcn_s_setprio(1);
      sa = MFMA16(pa_hi, t_hi[s2], sa);
      sa = MFMA16(pa_hi, t_lo[s2], sa);
      sa = MFMA16(pa_lo, t_hi[s2], sa);
      sb = MFMA16(pb_hi, t_hi[s2], sb);
      sb = MFMA16(pb_hi, t_lo[s2], sb);
      sb = MFMA16(pb_lo, t_hi[s2], sb);
      __builtin_amdgcn_s_setprio(0);

      const float ea0 = __expf(sa[0]), ea1 = __expf(sa[1]);
      const float ea2 = __expf(sa[2]), ea3 = __expf(sa[3]);
      const float eb0 = __expf(sb[0]), eb1 = __expf(sb[1]);
      const float eb2 = __expf(sb[2]), eb3 = __expf(sb[3]);
      denom[s2] += ((ea0 + ea1) + (ea2 + ea3)) + ((eb0 + eb1) + (eb2 + eb3));

      union { uint u[4]; bf16x8 v; } ph, pl;
      ph.u[0] = pk2(ea0, ea1); ph.u[1] = pk2(ea2, ea3);
      ph.u[2] = pk2(eb0, eb1); ph.u[3] = pk2(eb2, eb3);
      pl.u[0] = pk2(ea0 - up_lo(ph.u[0]), ea1 - up_hi(ph.u[0]));
      pl.u[1] = pk2(ea2 - up_lo(ph.u[1]), ea3 - up_hi(ph.u[1]));
      pl.u[2] = pk2(eb0 - up_lo(ph.u[2]), eb1 - up_hi(ph.u[2]));
      pl.u[3] = pk2(eb2 - up_lo(ph.u[3]), eb3 - up_hi(ph.u[3]));

      __builtin_amdgcn_s_setprio(1);
      acc0[s2] = MFMA16(ph.v, g0_hi, acc0[s2]);
      acc0[s2] = MFMA16(ph.v, g0_lo, acc0[s2]);
      acc0[s2] = MFMA16(pl.v, g0_hi, acc0[s2]);
      acc1[s2] = MFMA16(ph.v, g1_hi, acc1[s2]);
      acc1[s2] = MFMA16(ph.v, g1_lo, acc1[s2]);
      acc1[s2] = MFMA16(pl.v, g1_hi, acc1[s2]);
      __builtin_amdgcn_s_setprio(0);
    }

    __syncthreads();   // staged data landed; all reads of cur done
    cur ^= 1;
  }

  // epilogue: reuse staging LDS for the combine (all waves past final barrier)
  float* yl = (float*)&smem[0][0];        // [8][16][33]
  float* dl = yl + 8 * 16 * 33;           // [8][16]
  const int c  = tid & 31;
  const int qq = (tid >> 5) & 15;

#pragma unroll
  for (int s2 = 0; s2 < 2; ++s2) {
    float dn = denom[s2];
    dn += __shfl_xor(dn, 16);
    dn += __shfl_xor(dn, 32);
#pragma unroll
    for (int r = 0; r < 4; ++r) {
      yl[(w * 16 + 4 * g + r) * 33 + l15]      = acc0[s2][r];
      yl[(w * 16 + 4 * g + r) * 33 + 16 + l15] = acc1[s2][r];
    }
    if (g == 0) dl[w * 16 + l15] = dn;
    __syncthreads();

#pragma unroll
    for (int ws = 0; ws < 2; ++ws) {       // combine the 4 wk waves of half ws
      float y = 0.f, d = 0.f;
#pragma unroll
      for (int k2 = 0; k2 < 4; ++k2) {
        y += yl[((ws * 4 + k2) * 16 + qq) * 33 + c];
        d += dl[(ws * 4 + k2) * 16 + qq];
      }
      const int row = q_blk * 64 + (ws * 2 + s2) * 16 + qq;
      Yp[((size_t)(ks * BATCH + b)) * PB + row * 32 + c] = y;
      if (c == 0) Dp[((size_t)(ks * BATCH + b)) * HW + row] = d;
    }
    __syncthreads();
  }
}

// ---------------------------------------------------------------------------
// Kernel 4: final 1x1 conv fused with KSPLIT-way partial combine + normalize.
// yview[b][o][s] = sum_ks Yp / sum_ks Dp.  grid (25, B) x 256.
// ---------------------------------------------------------------------------
__global__ __launch_bounds__(256) void conv_out_kernel(
    const float* __restrict__ Yp, const float* __restrict__ Dp,
    const float* __restrict__ wy, const float* __restrict__ by,
    float* __restrict__ z) {
  const int b = blockIdx.y;
  const int s = blockIdx.x * 256 + threadIdx.x;

  __shared__ float wsm[CIN * COUT];   // 8 KiB, w_y is [CIN][COUT] row-major
  for (int i = threadIdx.x; i < CIN * COUT; i += 256) wsm[i] = wy[i];
  __syncthreads();

  float yr[COUT];
#pragma unroll
  for (int o = 0; o < COUT; ++o) {
    const int f = o * HW + s;
    const int n = f >> 5;
    float y = 0.f, d = 0.f;
#pragma unroll
    for (int ksi = 0; ksi < KSPLIT; ++ksi) {
      y += Yp[((size_t)(ksi * BATCH + b)) * PB + f];
      d += Dp[((size_t)(ksi * BATCH + b)) * HW + n];
    }
    yr[o] = y / d;
  }

  for (int i = 0; i < CIN; ++i) {
    const float4* wr = (const float4*)&wsm[i * COUT];
    float acc = 0.f;
#pragma unroll
    for (int q = 0; q < COUT / 4; ++q) {
      float4 wv = wr[q];
      acc += wv.x * yr[4*q] + wv.y * yr[4*q+1] + wv.z * yr[4*q+2] + wv.w * yr[4*q+3];
    }
    z[(size_t)b * XB + i * HW + s] = acc + by[i];
  }
}

// ---------------------------------------------------------------------------
extern "C" void kernel_launch(void* const* d_in, const int* in_sizes, int n_in,
                              void* d_out, int out_size, void* d_ws, size_t ws_size,
                              hipStream_t stream) {
  const float* x       = (const float*)d_in[0];
  const float* w_g     = (const float*)d_in[1];
  const float* b_g     = (const float*)d_in[2];
  const float* w_phi   = (const float*)d_in[3];
  const float* b_phi   = (const float*)d_in[4];
  const float* w_theta = (const float*)d_in[5];
  const float* b_theta = (const float*)d_in[6];
  const float* w_y     = (const float*)d_in[7];
  const float* b_y     = (const float*)d_in[8];
  float* z = (float*)d_out;

  char* base = (char*)d_ws;
  const size_t BF = (size_t)BATCH * PB * sizeof(ushort);  // 819200 B
  ushort* T_hi  = (ushort*)(base);
  ushort* T_lo  = (ushort*)(base + 1 * BF);
  ushort* P_hi  = (ushort*)(base + 2 * BF);
  ushort* P_lo  = (ushort*)(base + 3 * BF);
  ushort* G_hi  = (ushort*)(base + 4 * BF);
  ushort* G_lo  = (ushort*)(base + 5 * BF);
  ushort* Gt_hi = (ushort*)(base + 6 * BF);
  ushort* Gt_lo = (ushort*)(base + 7 * BF);
  float*  Yp    = (float*)(base + 8 * BF);                 // KSPLIT*B*PB f32
  float*  Dp    = (float*)(base + 8 * BF +
                           (size_t)KSPLIT * BATCH * PB * sizeof(float));

  conv3_kernel<<<dim3(25, 3, BATCH), 256, 0, stream>>>(
      x, w_theta, b_theta, w_phi, b_phi, w_g, b_g,
      T_hi, T_lo, P_hi, P_lo, G_hi, G_lo);
  transpose_g_kernel<<<dim3(200, BATCH), 256, 0, stream>>>(
      G_hi, G_lo, Gt_hi, Gt_lo);
  attn_kernel<<<dim3(100, KSPLIT, BATCH), 512, 0, stream>>>(
      T_hi, T_lo, P_hi, P_lo, Gt_hi, Gt_lo, Yp, Dp);
  conv_out_kernel<<<dim3(25, BATCH), 256, 0, stream>>>(Yp, Dp, w_y, b_y, z);
}